// Round 6
// baseline (2354.828 us; speedup 1.0000x reference)
//
#include <hip/hip_runtime.h>
#include <cstdint>
#include <cstddef>

#define HID 512
#define BATCH 4096
#define T_STEPS 20
#define NSTEP 19

typedef unsigned short ushort_t;
typedef __attribute__((ext_vector_type(8))) __bf16 bf16x8;
typedef __attribute__((ext_vector_type(4))) float f32x4;

typedef __attribute__((address_space(1))) void gvoid;
typedef __attribute__((address_space(3))) void lvoid;

// fp32 -> bf16 round-to-nearest-even
__device__ __forceinline__ unsigned short f2bf(float f) {
  unsigned int u = __float_as_uint(f);
  u += 0x7FFFu + ((u >> 16) & 1u);
  return (unsigned short)(u >> 16);
}

// async global->LDS 16B/lane; LDS base wave-uniform (HW adds lane*16)
__device__ __forceinline__ void load_lds16(const void* g, void* l) {
  __builtin_amdgcn_global_load_lds((gvoid*)g, (lvoid*)l, 16, 0, 0);
}

// pipeline barrier: ensure slab for THIS slot landed (all but 4 newest vmem
// done -> slab a complete; slab a+1's 4 chunks stay in flight), drain LDS ops,
// then workgroup barrier. Inline asm w/ memory clobber = compiler-level fence
// without the vmcnt(0) drain __syncthreads would impose (m97 stall).
__device__ __forceinline__ void pipe_barrier() {
  asm volatile("s_waitcnt vmcnt(4) lgkmcnt(0)\n\ts_barrier" ::: "memory");
}

// ---------------------------------------------------------------------------
// convw: weights fp32->bf16.
// Wcat2 [1536,512]: 16-row blocks b=prow/16: gate=b%3 (i,g,o), h-block=b/3.
//   => frags 3n,3n+1,3n+2 are i,g,o for h-cols [16n,16n+16).
// WoutB [512,512] plain.
// ---------------------------------------------------------------------------
__global__ __launch_bounds__(256) void convw_kernel(
    const float* __restrict__ Wi, const float* __restrict__ Wg,
    const float* __restrict__ Wo, const float* __restrict__ Wout,
    ushort_t* __restrict__ Wcat2, ushort_t* __restrict__ WoutB) {
  const int t = blockIdx.x * 256 + threadIdx.x;  // 1024x256 = 262144 groups of 4
  const float* src;
  ushort_t* dst;
  if (t < 196608) {
    int prow = t >> 7;
    int kk = (t & 127) * 4;
    int b = prow >> 4;
    int w16 = prow & 15;
    int gate = b % 3;
    int hh = (b / 3) * 16 + w16;
    src = (gate == 0 ? Wi : gate == 1 ? Wg : Wo) + (size_t)hh * HID + kk;
    dst = Wcat2 + (size_t)prow * HID + kk;
  } else {
    int t2 = t - 196608;
    int row = t2 >> 7;
    int kk = (t2 & 127) * 4;
    src = Wout + (size_t)row * HID + kk;
    dst = WoutB + (size_t)row * HID + kk;
  }
  float4 v = *(const float4*)src;
  union { unsigned short us[4]; uint2 u; } p;
  p.us[0] = f2bf(v.x); p.us[1] = f2bf(v.y); p.us[2] = f2bf(v.z); p.us[3] = f2bf(v.w);
  *(uint2*)dst = p.u;
}

// ---------------------------------------------------------------------------
// Persistent kernel: 256 blocks x 512 thr; block owns 16 batch rows, 19 steps.
// z in registers (waves 0-3, col = g*64+w*16+l16, row = quad*4+r).
// Weights streamed L2->LDS via async 32KB slabs (64 rows x 256 K), ring-3,
// raw-barrier pipeline. 65 slots/step: 48 gate + 1 gap + 16 out.
// ---------------------------------------------------------------------------
__global__ __launch_bounds__(512, 1) void persist_kernel(
    const float* __restrict__ y, const float* __restrict__ ts,
    const float* __restrict__ bout, const float* __restrict__ Wfc,
    const float* __restrict__ bfc, const ushort_t* __restrict__ Wcat2,
    const ushort_t* __restrict__ WoutB, float* __restrict__ out) {
  __shared__ ushort_t wbuf[3][64 * 256];  // 3 x 32 KB slab ring (xor-swizzled)
  __shared__ ushort_t zbl[16 * 512];      // chunk-major: ((qk*16+row)*8+j)
  __shared__ ushort_t dhl[16 * 512];      // same layout
  __shared__ float glog[12 * 256];        // gate-logit frag ring [ring][col*16+row4]
  __shared__ float redm[4 * 16];
  __shared__ float redA[4 * 16];
  __shared__ float redB[4 * 16];

  const int tid = threadIdx.x;
  const int w = tid >> 6;       // wave
  const int lane = tid & 63;
  const int quad = lane >> 4;
  const int l16 = lane & 15;
  const int b0 = blockIdx.x * 16;
  const float bfc0 = bfc[0];

  // per-wave column constants (waves 0-3): col(g) = g*64 + w*16 + l16
  float bo8[8], wf8[8];
  if (w < 4) {
#pragma unroll
    for (int g = 0; g < 8; ++g) {
      int col = g * 64 + w * 16 + l16;
      bo8[g] = bout[col];
      wf8[g] = Wfc[col];
    }
  }

  // ---- slab stage issue for global slot index tgt ----
  auto issue = [&](int tgt) {
    int q = tgt % 65;
    const ushort_t* src;
    if (q < 48)      src = Wcat2 + (size_t)(64 * (q >> 1)) * HID + (q & 1) * 256;
    else if (q == 48) src = WoutB;  // dummy (never consumed)
    else { int j = q - 49; src = WoutB + (size_t)(64 * (j >> 1)) * HID + (j & 1) * 256; }
    ushort_t* dst = &wbuf[tgt % 3][0];
#pragma unroll
    for (int c = 0; c < 4; ++c) {
      int i = w * 4 + c;                 // instr 0..31
      int row = 2 * i + (lane >> 5);     // slab row 0..63
      int qkp = lane & 31;               // physical k-chunk
      int qkl = qkp ^ (row & 31);        // logical k-chunk (xor swizzle)
      load_lds16(src + (size_t)row * HID + qkl * 8, dst + i * 512);
    }
  };

  // ---- init: z = y (regs), zbl = bf16(y) ----
  float z8[8][4];
  if (w < 4) {
#pragma unroll
    for (int g = 0; g < 8; ++g) {
      int col = g * 64 + w * 16 + l16;
#pragma unroll
      for (int r = 0; r < 4; ++r) {
        int row = quad * 4 + r;
        float v = y[(size_t)(b0 + row) * HID + col];
        z8[g][r] = v;
        zbl[((col >> 3) * 16 + row) * 8 + (col & 7)] = f2bf(v);
      }
    }
  }
  __syncthreads();

  // readout helper pattern is inlined twice (init t=0 and per-step t+1)
  // ---- readout for t = 0 ----
  {
    float mr[4];
    if (w < 4) {
#pragma unroll
      for (int r = 0; r < 4; ++r) {
        float pm = z8[0][r];
#pragma unroll
        for (int g = 1; g < 8; ++g) pm = fmaxf(pm, z8[g][r]);
#pragma unroll
        for (int off = 1; off < 16; off <<= 1) pm = fmaxf(pm, __shfl_xor(pm, off));
        mr[r] = pm;
        if (l16 == 0) redm[w * 16 + quad * 4 + r] = pm;
      }
    }
    __syncthreads();
    if (w < 4) {
#pragma unroll
      for (int r = 0; r < 4; ++r) {
        float m = redm[quad * 4 + r];
#pragma unroll
        for (int ww = 1; ww < 4; ++ww) m = fmaxf(m, redm[ww * 16 + quad * 4 + r]);
        mr[r] = m;
      }
    }
    __syncthreads();
    if (w < 4) {
#pragma unroll
      for (int r = 0; r < 4; ++r) {
        float ps = 0.f, pd = 0.f;
#pragma unroll
        for (int g = 0; g < 8; ++g) {
          float e = expf(z8[g][r] - mr[r]);
          ps += e;
          pd += e * wf8[g];
        }
#pragma unroll
        for (int off = 1; off < 16; off <<= 1) {
          ps += __shfl_xor(ps, off);
          pd += __shfl_xor(pd, off);
        }
        if (l16 == 0) { redA[w * 16 + quad * 4 + r] = ps; redB[w * 16 + quad * 4 + r] = pd; }
      }
    }
    __syncthreads();
    if (tid < 16) {
      float s = 0.f, d = 0.f;
#pragma unroll
      for (int ww = 0; ww < 4; ++ww) { s += redA[ww * 16 + tid]; d += redB[ww * 16 + tid]; }
      out[(size_t)(b0 + tid) * T_STEPS] = d / s + bfc0;
    }
    __syncthreads();
  }

  // ---- prologue staging ----
  issue(0);
  issue(1);

  int a = 0;  // global slot counter
  for (int t = 0; t < NSTEP; ++t) {
    const float dt = ts[t + 1] - ts[t];

    // A-operand frags (zb) into regs; reloaded from dhl at slot 49
    bf16x8 aop[16];
    if (w < 4) {
#pragma unroll
      for (int ks = 0; ks < 16; ++ks)
        aop[ks] = *(const bf16x8*)&zbl[((ks * 4 + quad) * 16 + l16) * 8];
    }

    f32x4 accg = {0.f, 0.f, 0.f, 0.f};
    f32x4 acc8[8] = {};
    int na = 0;

    for (int q = 0; q < 65; ++q, ++a) {
      pipe_barrier();          // vmcnt(4): slab a landed; lgkm drained
      issue(a + 2);
      const ushort_t* buf = &wbuf[a % 3][0];

      if (q < 48) {
        // ---- gate slots ----
        if (w < 4) {
          const int half = q & 1;
          if (half == 0) accg = (f32x4){0.f, 0.f, 0.f, 0.f};
          const int rowb = w * 16 + l16;
#pragma unroll
          for (int c = 0; c < 8; ++c) {
            int qkp = (c * 4 + quad) ^ (rowb & 31);
            bf16x8 bfr = *(const bf16x8*)&buf[rowb * 256 + qkp * 8];
            accg = __builtin_amdgcn_mfma_f32_16x16x32_bf16(aop[half * 8 + c], bfr, accg, 0, 0, 0);
          }
          if (half == 1) {
            int ring = (4 * (q >> 1) + w) % 12;
            *(f32x4*)&glog[ring * 256 + l16 * 16 + quad * 4] = accg;
          }
        } else {
          // ---- act pipeline (waves 4-7) ----
          int pairs_done = q >> 1;
          while (3 * na + 2 < 4 * pairs_done) {
            if (w == 4 + (na & 3)) {
              f32x4 vi = *(const f32x4*)&glog[((3 * na) % 12) * 256 + l16 * 16 + quad * 4];
              f32x4 vg = *(const f32x4*)&glog[((3 * na + 1) % 12) * 256 + l16 * 16 + quad * 4];
              f32x4 vo = *(const f32x4*)&glog[((3 * na + 2) % 12) * 256 + l16 * 16 + quad * 4];
              int col = 16 * na + l16;
#pragma unroll
              for (int r = 0; r < 4; ++r) {
                float si = 1.f / (1.f + expf(-vi[r]));
                float tg = tanhf(vg[r]);
                float so = 1.f / (1.f + expf(-vo[r]));
                dhl[((col >> 3) * 16 + quad * 4 + r) * 8 + (col & 7)] =
                    f2bf(so * tanhf(si * tg));
              }
            }
            ++na;
          }
        }
      } else if (q == 48) {
        // gap slot: final acts (n up to 31)
        if (w >= 4) {
          while (3 * na + 2 < 96) {
            if (w == 4 + (na & 3)) {
              f32x4 vi = *(const f32x4*)&glog[((3 * na) % 12) * 256 + l16 * 16 + quad * 4];
              f32x4 vg = *(const f32x4*)&glog[((3 * na + 1) % 12) * 256 + l16 * 16 + quad * 4];
              f32x4 vo = *(const f32x4*)&glog[((3 * na + 2) % 12) * 256 + l16 * 16 + quad * 4];
              int col = 16 * na + l16;
#pragma unroll
              for (int r = 0; r < 4; ++r) {
                float si = 1.f / (1.f + expf(-vi[r]));
                float tg = tanhf(vg[r]);
                float so = 1.f / (1.f + expf(-vo[r]));
                dhl[((col >> 3) * 16 + quad * 4 + r) * 8 + (col & 7)] =
                    f2bf(so * tanhf(si * tg));
              }
            }
            ++na;
          }
        }
      } else {
        // ---- out slots (q 49..64) ----
        if (w < 4) {
          if (q == 49) {
#pragma unroll
            for (int ks = 0; ks < 16; ++ks)
              aop[ks] = *(const bf16x8*)&dhl[((ks * 4 + quad) * 16 + l16) * 8];
          }
          const int j = q - 49, g = j >> 1, half = j & 1;
          const int rowb = w * 16 + l16;
#pragma unroll
          for (int c = 0; c < 8; ++c) {
            int qkp = (c * 4 + quad) ^ (rowb & 31);
            bf16x8 bfr = *(const bf16x8*)&buf[rowb * 256 + qkp * 8];
            acc8[g] = __builtin_amdgcn_mfma_f32_16x16x32_bf16(aop[half * 8 + c], bfr, acc8[g], 0, 0, 0);
          }
        }
      }
    }

    // ---- update region ----
    __syncthreads();  // drains outstanding prefetches (once per step) + sync
    float e8[8][4];
    float mr[4], inv4[4];
    if (w < 4) {
#pragma unroll
      for (int g = 0; g < 8; ++g)
#pragma unroll
        for (int r = 0; r < 4; ++r) acc8[g][r] += bo8[g];
#pragma unroll
      for (int r = 0; r < 4; ++r) {
        float pm = acc8[0][r];
#pragma unroll
        for (int g = 1; g < 8; ++g) pm = fmaxf(pm, acc8[g][r]);
#pragma unroll
        for (int off = 1; off < 16; off <<= 1) pm = fmaxf(pm, __shfl_xor(pm, off));
        if (l16 == 0) redm[w * 16 + quad * 4 + r] = pm;
      }
    }
    __syncthreads();
    if (w < 4) {
#pragma unroll
      for (int r = 0; r < 4; ++r) {
        float m = redm[quad * 4 + r];
#pragma unroll
        for (int ww = 1; ww < 4; ++ww) m = fmaxf(m, redm[ww * 16 + quad * 4 + r]);
        mr[r] = m;
      }
    }
    __syncthreads();
    if (w < 4) {
#pragma unroll
      for (int r = 0; r < 4; ++r) {
        float ps = 0.f;
#pragma unroll
        for (int g = 0; g < 8; ++g) {
          e8[g][r] = expf(acc8[g][r] - mr[r]);
          ps += e8[g][r];
        }
#pragma unroll
        for (int off = 1; off < 16; off <<= 1) ps += __shfl_xor(ps, off);
        if (l16 == 0) redm[w * 16 + quad * 4 + r] = ps;
      }
    }
    __syncthreads();
    if (w < 4) {
#pragma unroll
      for (int r = 0; r < 4; ++r) {
        float s = 0.f;
#pragma unroll
        for (int ww = 0; ww < 4; ++ww) s += redm[ww * 16 + quad * 4 + r];
        inv4[r] = 1.f / s;
      }
      // z += dt * softmax ; rebuild zbl
#pragma unroll
      for (int g = 0; g < 8; ++g) {
        int col = g * 64 + w * 16 + l16;
#pragma unroll
        for (int r = 0; r < 4; ++r) {
          float v = z8[g][r] + dt * e8[g][r] * inv4[r];
          z8[g][r] = v;
          zbl[((col >> 3) * 16 + quad * 4 + r) * 8 + (col & 7)] = f2bf(v);
        }
      }
    }
    __syncthreads();
    // ---- readout t+1: softmax(z_new) . Wfc + bfc ----
    if (w < 4) {
#pragma unroll
      for (int r = 0; r < 4; ++r) {
        float pm = z8[0][r];
#pragma unroll
        for (int g = 1; g < 8; ++g) pm = fmaxf(pm, z8[g][r]);
#pragma unroll
        for (int off = 1; off < 16; off <<= 1) pm = fmaxf(pm, __shfl_xor(pm, off));
        if (l16 == 0) redm[w * 16 + quad * 4 + r] = pm;
      }
    }
    __syncthreads();
    if (w < 4) {
#pragma unroll
      for (int r = 0; r < 4; ++r) {
        float m = redm[quad * 4 + r];
#pragma unroll
        for (int ww = 1; ww < 4; ++ww) m = fmaxf(m, redm[ww * 16 + quad * 4 + r]);
        mr[r] = m;
      }
#pragma unroll
      for (int r = 0; r < 4; ++r) {
        float ps = 0.f, pd = 0.f;
#pragma unroll
        for (int g = 0; g < 8; ++g) {
          float e = expf(z8[g][r] - mr[r]);
          ps += e;
          pd += e * wf8[g];
        }
#pragma unroll
        for (int off = 1; off < 16; off <<= 1) {
          ps += __shfl_xor(ps, off);
          pd += __shfl_xor(pd, off);
        }
        if (l16 == 0) { redA[w * 16 + quad * 4 + r] = ps; redB[w * 16 + quad * 4 + r] = pd; }
      }
    }
    __syncthreads();
    if (tid < 16) {
      float s = 0.f, d = 0.f;
#pragma unroll
      for (int ww = 0; ww < 4; ++ww) { s += redA[ww * 16 + tid]; d += redB[ww * 16 + tid]; }
      out[(size_t)(b0 + tid) * T_STEPS + t + 1] = d / s + bfc0;
    }
    __syncthreads();
  }
}

extern "C" void kernel_launch(void* const* d_in, const int* in_sizes, int n_in,
                              void* d_out, int out_size, void* d_ws, size_t ws_size,
                              hipStream_t stream) {
  const float* y    = (const float*)d_in[0];
  const float* ts   = (const float*)d_in[1];
  const float* Wi   = (const float*)d_in[2];
  // d_in[3] = Wf: computed-but-unused in reference -> skipped
  const float* Wg   = (const float*)d_in[4];
  const float* Wo   = (const float*)d_in[5];
  const float* Wout = (const float*)d_in[6];
  const float* bout = (const float*)d_in[7];
  const float* Wfc  = (const float*)d_in[8];
  const float* bfc  = (const float*)d_in[9];
  float* out = (float*)d_out;

  char* ws = (char*)d_ws;
  ushort_t* Wcat2 = (ushort_t*)(ws);            // 1536*512*2 = 1572864
  ushort_t* WoutB = (ushort_t*)(ws + 1572864);  // 512*512*2  = 524288

  convw_kernel<<<1024, 256, 0, stream>>>(Wi, Wg, Wo, Wout, Wcat2, WoutB);
  persist_kernel<<<BATCH / 16, 512, 0, stream>>>(y, ts, bout, Wfc, bfc,
                                                 Wcat2, WoutB, out);
}